// Round 1
// baseline (3010.996 us; speedup 1.0000x reference)
//
#include <hip/hip_runtime.h>
#include <stdint.h>

// ---------------- problem constants ----------------
#define S_LEN   8192
#define DMODEL  3072
#define HDIM    768
#define NLM     32
#define MTOK    16384          // B*S token rows
#define MV      16448          // + 2*32 landmark rows (valid GEMM rows)
#define MP      16512          // padded to 129*128
#define NQKV    9216
#define KDIM    3072
#define SCALE_F 0.036084391824351615f   // 1/sqrt(768)

// ---------------- workspace layout (bytes) ----------------
// A        bf16 [MP][3072]          (dead after GEMM1; region reused for PROJ)
// Wt       bf16 [12288][3072]       rows: Wq^T|Wk^T|Wv^T|Wo^T
// QKV      bf16 [MV][9216]          cols: Q|K|V, head h at h*768
// CTX      bf16 [MP][3072]          rows 0..16383 global ctx, 16384.. landmark ctx
// bcat     f32  [12288]             bq|bk|bv|bo
// part/ml  f32  landmark-attn partial softmax states (32 k-chunks)
#define OFF_A    ((size_t)0)
#define OFF_WT   ((size_t)101449728)
#define OFF_QKV  ((size_t)176947200)
#define OFF_CTX  ((size_t)480116736)
#define OFF_BCAT ((size_t)581566464)
#define OFF_PART ((size_t)581615616)
#define OFF_ML   ((size_t)606781440)

#if defined(__has_builtin)
#if __has_builtin(__builtin_amdgcn_global_load_lds)
#define USE_GLL 1
#endif
#endif
#ifndef USE_GLL
#define USE_GLL 0
#endif

typedef __attribute__((ext_vector_type(8))) short bf8_t;             // 8 bf16 (4 VGPR) MFMA frag
typedef __attribute__((ext_vector_type(4))) float f4_t;
typedef __attribute__((ext_vector_type(4))) short s4_t;
typedef __attribute__((ext_vector_type(4))) unsigned short us4_t;

__device__ __forceinline__ float b2f(unsigned short u) {
  unsigned x = ((unsigned)u) << 16;
  float f;
  __builtin_memcpy(&f, &x, 4);
  return f;
}
__device__ __forceinline__ unsigned short f2b(float f) {  // RNE bf16
  unsigned x;
  __builtin_memcpy(&x, &f, 4);
  x += 0x7fffu + ((x >> 16) & 1u);
  return (unsigned short)(x >> 16);
}
__device__ __forceinline__ void load12(const unsigned short* p, float* f) {
  s4_t v0 = *(const s4_t*)p;
  s4_t v1 = *(const s4_t*)(p + 4);
  s4_t v2 = *(const s4_t*)(p + 8);
#pragma unroll
  for (int e = 0; e < 4; ++e) {
    f[e]     = b2f((unsigned short)v0[e]);
    f[4 + e] = b2f((unsigned short)v1[e]);
    f[8 + e] = b2f((unsigned short)v2[e]);
  }
}
__device__ __forceinline__ void store12(unsigned short* p, const float* f) {
  us4_t a = {f2b(f[0]), f2b(f[1]), f2b(f[2]), f2b(f[3])};
  us4_t b = {f2b(f[4]), f2b(f[5]), f2b(f[6]), f2b(f[7])};
  us4_t c = {f2b(f[8]), f2b(f[9]), f2b(f[10]), f2b(f[11])};
  *(us4_t*)p = a;
  *(us4_t*)(p + 4) = b;
  *(us4_t*)(p + 8) = c;
}

// ---------------- K: concatenated bias vector ----------------
__global__ __launch_bounds__(256) void build_bcat(const float* __restrict__ bq,
                                                  const float* __restrict__ bk,
                                                  const float* __restrict__ bv,
                                                  const float* __restrict__ bo,
                                                  float* __restrict__ bcat) {
  int n = blockIdx.x * 256 + threadIdx.x;            // 0..12287
  float v = (n < 3072) ? bq[n] : (n < 6144) ? bk[n - 3072]
          : (n < 9216) ? bv[n - 6144] : bo[n - 9216];
  bcat[n] = v;
}

// ---------------- K0: A matrix (tokens + landmark tokens), fp32 -> bf16 ----------------
__global__ __launch_bounds__(256) void build_a(const float* __restrict__ hs,
                                               const float* __restrict__ lemb,
                                               unsigned short* __restrict__ A) {
  size_t idx = (size_t)blockIdx.x * 256 + threadIdx.x;
  size_t e = idx * 4;
  int row = (int)(e / DMODEL);
  int col = (int)(e - (size_t)row * DMODEL);
  f4_t v;
  if (row < MTOK) {
    v = *(const f4_t*)(hs + e);
  } else if (row < MV) {
    int r2 = row - MTOK;
    int b = r2 >> 5, j = r2 & 31;
    int sel = (j * 511) / 31;          // matches linspace(0,511,32) truncation
    int li = sel * 16;
    f4_t a = *(const f4_t*)(hs + ((size_t)(b * S_LEN + li)) * DMODEL + col);
    f4_t c = *(const f4_t*)(lemb + (size_t)j * DMODEL + col);
    v = a + c;
  } else {
    v = (f4_t){0.f, 0.f, 0.f, 0.f};    // pad rows (stores masked later anyway)
  }
  us4_t o = {f2b(v[0]), f2b(v[1]), f2b(v[2]), f2b(v[3])};
  *(us4_t*)(A + e) = o;
}

// ---------------- K1: weight transpose, fp32 [K][N] -> bf16 [N][K] ----------------
__global__ __launch_bounds__(256) void wtrans(const float* __restrict__ W,
                                              unsigned short* __restrict__ Wt) {
  __shared__ float t[32][33];
  int n0 = blockIdx.x * 32, k0 = blockIdx.y * 32;
  int x = threadIdx.x, y = threadIdx.y;              // block (32,8)
#pragma unroll
  for (int i = 0; i < 4; ++i)
    t[y + i * 8][x] = W[(size_t)(k0 + y + i * 8) * DMODEL + n0 + x];
  __syncthreads();
#pragma unroll
  for (int i = 0; i < 4; ++i)
    Wt[(size_t)(n0 + y + i * 8) * DMODEL + k0 + x] = f2b(t[x][y + i * 8]);
}

// ---------------- K2: bf16 MFMA GEMM, C[M][N] = A[M][K] * Bt[N][K]^T + bias ----------------
// 128x128 tile, BK=64, 4 waves of 4x4 mfma_f32_16x16x32_bf16, global_load_lds staging.
__global__ __launch_bounds__(256) void gemm_bt(const unsigned short* __restrict__ A,
                                               const unsigned short* __restrict__ Bt,
                                               const float* __restrict__ bias,
                                               unsigned short* __restrict__ C,
                                               int Mvalid, int N) {
  __shared__ unsigned short As[128 * 64];
  __shared__ unsigned short Bs[128 * 64];
  const int tid = threadIdx.x;
  const int lane = tid & 63;
  const int wave = tid >> 6;
  const int wm = wave & 1, wn = wave >> 1;
  const int row16 = lane & 15, quad = lane >> 4;
  const int tileN = blockIdx.x * 128;
  const int tileM = blockIdx.y * 128;

  f4_t acc[4][4];
#pragma unroll
  for (int a = 0; a < 4; ++a)
#pragma unroll
    for (int b = 0; b < 4; ++b) acc[a][b] = (f4_t){0.f, 0.f, 0.f, 0.f};

  // staging map: chunk li = i*256+tid, row=li>>3 (=i*32 + tid>>3), col=(tid&7)*8, 16B each
  const int scol = (tid & 7) * 8;
  const int srow = tid >> 3;                          // 0..31
  const unsigned short* gA = A + (size_t)(tileM + srow) * KDIM + scol;
  const unsigned short* gB = Bt + (size_t)(tileN + srow) * KDIM + scol;
#if USE_GLL
  char* lAbase = (char*)As + ((tid & 192) * 16);      // wave-uniform base; HW adds lane*16
  char* lBbase = (char*)Bs + ((tid & 192) * 16);
#endif

  for (int kt = 0; kt < KDIM; kt += 64) {
#pragma unroll
    for (int i = 0; i < 4; ++i) {
#if USE_GLL
      __builtin_amdgcn_global_load_lds(
          (const __attribute__((address_space(1))) void*)(gA + (size_t)(i * 32) * KDIM + kt),
          (__attribute__((address_space(3))) void*)(lAbase + i * 4096), 16, 0, 0);
      __builtin_amdgcn_global_load_lds(
          (const __attribute__((address_space(1))) void*)(gB + (size_t)(i * 32) * KDIM + kt),
          (__attribute__((address_space(3))) void*)(lBbase + i * 4096), 16, 0, 0);
#else
      *(bf8_t*)((char*)As + (size_t)(i * 256 + tid) * 16) =
          *(const bf8_t*)(gA + (size_t)(i * 32) * KDIM + kt);
      *(bf8_t*)((char*)Bs + (size_t)(i * 256 + tid) * 16) =
          *(const bf8_t*)(gB + (size_t)(i * 32) * KDIM + kt);
#endif
    }
    __syncthreads();
#pragma unroll
    for (int kk = 0; kk < 2; ++kk) {
      bf8_t af[4], bfr[4];
#pragma unroll
      for (int mi = 0; mi < 4; ++mi)
        af[mi] = *(const bf8_t*)(As + (wm * 64 + mi * 16 + row16) * 64 + kk * 32 + quad * 8);
#pragma unroll
      for (int ni = 0; ni < 4; ++ni)
        bfr[ni] = *(const bf8_t*)(Bs + (wn * 64 + ni * 16 + row16) * 64 + kk * 32 + quad * 8);
#pragma unroll
      for (int mi = 0; mi < 4; ++mi)
#pragma unroll
        for (int ni = 0; ni < 4; ++ni)
          acc[mi][ni] = __builtin_amdgcn_mfma_f32_16x16x32_bf16(af[mi], bfr[ni], acc[mi][ni], 0, 0, 0);
    }
    __syncthreads();
  }

  // epilogue: D[m= wm*64+mi*16+quad*4+i][n= wn*64+ni*16+row16]  (verified C/D map)
  float bv_[4];
#pragma unroll
  for (int ni = 0; ni < 4; ++ni) bv_[ni] = bias[tileN + wn * 64 + ni * 16 + row16];
#pragma unroll
  for (int mi = 0; mi < 4; ++mi) {
#pragma unroll
    for (int i = 0; i < 4; ++i) {
      int grow = tileM + wm * 64 + mi * 16 + quad * 4 + i;
      if (grow < Mvalid) {
        size_t base = (size_t)grow * N + tileN + wn * 64 + row16;
#pragma unroll
        for (int ni = 0; ni < 4; ++ni)
          C[base + ni * 16] = f2b(acc[mi][ni][i] + bv_[ni]);
      }
    }
  }
}

// ---------------- K3: global attention (every token over 32 landmarks), wave per (r,h) ----------------
__global__ __launch_bounds__(256) void glob_attn(const unsigned short* __restrict__ QKV,
                                                 unsigned short* __restrict__ CTX) {
  int wid = blockIdx.x * 4 + (threadIdx.x >> 6);     // 0..65535
  int lane = threadIdx.x & 63;
  int rr = wid & (S_LEN - 1);
  int bh = wid >> 13;
  int b = bh >> 2, h = bh & 3;
  size_t qrow = (size_t)(b * S_LEN + rr);

  float q[12];
  load12(QKV + qrow * NQKV + h * HDIM + lane * 12, q);

  const unsigned short* Kb = QKV + (size_t)(MTOK + b * NLM) * NQKV + DMODEL + h * HDIM + lane * 12;
  float sloc = 0.f;
  for (int j = 0; j < NLM; ++j) {
    float kv[12];
    load12(Kb + (size_t)j * NQKV, kv);
    float p = 0.f;
#pragma unroll
    for (int e = 0; e < 12; ++e) p += q[e] * kv[e];
#pragma unroll
    for (int off = 32; off; off >>= 1) p += __shfl_xor(p, off);
    if ((lane & 31) == j) sloc = p * SCALE_F;
  }
  float m = sloc;
#pragma unroll
  for (int off = 16; off; off >>= 1) m = fmaxf(m, __shfl_xor(m, off));
  float p = __expf(sloc - m);
  float l = p;
#pragma unroll
  for (int off = 16; off; off >>= 1) l += __shfl_xor(l, off);
  float w = p / l;

  float ctx[12];
#pragma unroll
  for (int e = 0; e < 12; ++e) ctx[e] = 0.f;
  const unsigned short* Vb = QKV + (size_t)(MTOK + b * NLM) * NQKV + 2 * DMODEL + h * HDIM + lane * 12;
  for (int j = 0; j < NLM; ++j) {
    float wj = __shfl(w, j);
    float vv[12];
    load12(Vb + (size_t)j * NQKV, vv);
#pragma unroll
    for (int e = 0; e < 12; ++e) ctx[e] += wj * vv[e];
  }
  store12(CTX + qrow * DMODEL + h * HDIM + lane * 12, ctx);
}

// ---------------- K4: landmark attention partials (online softmax, 32 k-chunks x 256) ----------------
__global__ __launch_bounds__(256) void lm_attn_part(const unsigned short* __restrict__ QKV,
                                                    float* __restrict__ ctxpart,
                                                    float* __restrict__ mlpart) {
  int wid = blockIdx.x * 4 + (threadIdx.x >> 6);     // 0..8191
  int lane = threadIdx.x & 63;
  int kc = wid & 31, j = (wid >> 5) & 31, h = (wid >> 10) & 3, b = wid >> 12;

  float q[12];
  load12(QKV + (size_t)(MTOK + b * NLM + j) * NQKV + h * HDIM + lane * 12, q);

  float m = -1e30f, l = 0.f, ctx[12];
#pragma unroll
  for (int e = 0; e < 12; ++e) ctx[e] = 0.f;

  for (int k = kc * 256; k < kc * 256 + 256; ++k) {
    size_t row = (size_t)(b * S_LEN + k);
    float kv[12], vv[12];
    load12(QKV + row * NQKV + DMODEL + h * HDIM + lane * 12, kv);
    float s = 0.f;
#pragma unroll
    for (int e = 0; e < 12; ++e) s += q[e] * kv[e];
#pragma unroll
    for (int off = 32; off; off >>= 1) s += __shfl_xor(s, off);
    s *= SCALE_F;
    load12(QKV + row * NQKV + 2 * DMODEL + h * HDIM + lane * 12, vv);
    if (s <= m) {                                    // wave-uniform branch
      float pp = __expf(s - m);
      l += pp;
#pragma unroll
      for (int e = 0; e < 12; ++e) ctx[e] += pp * vv[e];
    } else {
      float al = __expf(m - s);
      m = s;
      l = l * al + 1.f;
#pragma unroll
      for (int e = 0; e < 12; ++e) ctx[e] = ctx[e] * al + vv[e];
    }
  }
  float* cp = ctxpart + (size_t)wid * HDIM + lane * 12;
#pragma unroll
  for (int e = 0; e < 12; ++e) cp[e] = ctx[e];
  if (lane == 0) {
    mlpart[wid * 2] = m;
    mlpart[wid * 2 + 1] = l;
  }
}

// ---------------- K4b: merge landmark partials, wave per (b,h,j) ----------------
__global__ __launch_bounds__(256) void lm_combine(const float* __restrict__ ctxpart,
                                                  const float* __restrict__ mlpart,
                                                  unsigned short* __restrict__ CTX) {
  int wid = blockIdx.x * 4 + (threadIdx.x >> 6);     // 0..255
  int lane = threadIdx.x & 63;
  int j = wid & 31, h = (wid >> 5) & 3, b = wid >> 7;
  int base = wid * 32;
  int kcl = lane & 31;
  float mk = mlpart[(base + kcl) * 2];
  float lk = mlpart[(base + kcl) * 2 + 1];
  float mm = mk;
#pragma unroll
  for (int off = 16; off; off >>= 1) mm = fmaxf(mm, __shfl_xor(mm, off));
  float al = __expf(mk - mm);
  float ls = al * lk;
#pragma unroll
  for (int off = 16; off; off >>= 1) ls += __shfl_xor(ls, off);

  float ctx[12];
#pragma unroll
  for (int e = 0; e < 12; ++e) ctx[e] = 0.f;
  for (int kc = 0; kc < 32; ++kc) {
    float a = __shfl(al, kc);
    const float* cp = ctxpart + (size_t)(base + kc) * HDIM + lane * 12;
#pragma unroll
    for (int e = 0; e < 12; ++e) ctx[e] += a * cp[e];
  }
  float inv = 1.f / ls;
#pragma unroll
  for (int e = 0; e < 12; ++e) ctx[e] *= inv;
  store12(CTX + (size_t)(MTOK + b * NLM + j) * DMODEL + h * HDIM + lane * 12, ctx);
}

// ---------------- K6: out = (landmark? lm_proj : hs) + global_proj ----------------
__global__ __launch_bounds__(256) void compose(const float* __restrict__ hs,
                                               const unsigned short* __restrict__ PROJ,
                                               float* __restrict__ out) {
  size_t idx = (size_t)blockIdx.x * 256 + threadIdx.x;
  size_t e = idx * 4;
  int row = (int)(e / DMODEL);
  int col = (int)(e - (size_t)row * DMODEL);
  int b = row >> 13, s = row & (S_LEN - 1);

  us4_t g4 = *(const us4_t*)(PROJ + (size_t)row * DMODEL + col);
  int j = -1;
  if ((s & 15) == 0) {
    int sel = s >> 4;
    int jc = (sel * 31 + 510) / 511;                 // ceil(sel*31/511): unique candidate
    if (jc < 32 && (jc * 511) / 31 == sel) j = jc;
  }
  f4_t base;
  if (j >= 0) {
    us4_t l4 = *(const us4_t*)(PROJ + (size_t)(MTOK + b * NLM + j) * DMODEL + col);
    base = (f4_t){b2f(l4[0]), b2f(l4[1]), b2f(l4[2]), b2f(l4[3])};
  } else {
    base = *(const f4_t*)(hs + e);
  }
  f4_t o = {base[0] + b2f(g4[0]), base[1] + b2f(g4[1]),
            base[2] + b2f(g4[2]), base[3] + b2f(g4[3])};
  *(f4_t*)(out + e) = o;
}

// ---------------- launch ----------------
extern "C" void kernel_launch(void* const* d_in, const int* in_sizes, int n_in,
                              void* d_out, int out_size, void* d_ws, size_t ws_size,
                              hipStream_t stream) {
  const float* hs   = (const float*)d_in[0];
  const float* lemb = (const float*)d_in[1];
  const float* Wq   = (const float*)d_in[2];
  const float* bq   = (const float*)d_in[3];
  const float* Wk   = (const float*)d_in[4];
  const float* bk   = (const float*)d_in[5];
  const float* Wv   = (const float*)d_in[6];
  const float* bv   = (const float*)d_in[7];
  const float* Wo   = (const float*)d_in[8];
  const float* bo   = (const float*)d_in[9];
  float* out = (float*)d_out;
  char* ws = (char*)d_ws;

  unsigned short* A    = (unsigned short*)(ws + OFF_A);
  unsigned short* Wt   = (unsigned short*)(ws + OFF_WT);
  unsigned short* QKV  = (unsigned short*)(ws + OFF_QKV);
  unsigned short* CTX  = (unsigned short*)(ws + OFF_CTX);
  float*          bcat = (float*)(ws + OFF_BCAT);
  float*          part = (float*)(ws + OFF_PART);
  float*          ml   = (float*)(ws + OFF_ML);
  unsigned short* PROJ = (unsigned short*)(ws + OFF_A);  // A dead after GEMM1; reuse

  build_bcat<<<dim3(48), dim3(256), 0, stream>>>(bq, bk, bv, bo, bcat);
  build_a<<<dim3(49536), dim3(256), 0, stream>>>(hs, lemb, A);
  wtrans<<<dim3(96, 96), dim3(32, 8), 0, stream>>>(Wq, Wt);
  wtrans<<<dim3(96, 96), dim3(32, 8), 0, stream>>>(Wk, Wt + (size_t)3072 * KDIM);
  wtrans<<<dim3(96, 96), dim3(32, 8), 0, stream>>>(Wv, Wt + (size_t)6144 * KDIM);
  wtrans<<<dim3(96, 96), dim3(32, 8), 0, stream>>>(Wo, Wt + (size_t)9216 * KDIM);

  // QKV for tokens + landmarks in one GEMM: [16448, 9216]
  gemm_bt<<<dim3(NQKV / 128, MP / 128), dim3(256), 0, stream>>>(A, Wt, bcat, QKV, MV, NQKV);

  glob_attn<<<dim3(16384), dim3(256), 0, stream>>>(QKV, CTX);
  lm_attn_part<<<dim3(2048), dim3(256), 0, stream>>>(QKV, part, ml);
  lm_combine<<<dim3(64), dim3(256), 0, stream>>>(part, ml, CTX);

  // output projection for both ctx sets: [16448, 3072]
  gemm_bt<<<dim3(DMODEL / 128, MP / 128), dim3(256), 0, stream>>>(
      CTX, Wt + (size_t)9216 * KDIM, bcat + 9216, PROJ, MV, DMODEL);

  compose<<<dim3(49152), dim3(256), 0, stream>>>(hs, PROJ, out);
}